// Round 1
// 392.214 us; speedup vs baseline: 1.1683x; 1.1683x over previous
//
#include <hip/hip_runtime.h>
#include <hip/hip_bf16.h>
#include <math.h>

#define N_NODES 40000
#define NE      640000
#define FIN     33
#define H       128
#define COUT    3
#define NLAYERS 8
#define ALPHA   0.1f
#define THETA   0.5f
#define CAP     96             // max bucket capacity; deg ~ Poisson(16), P(>96) ~ 1e-40

// setup mega-kernel block ranges
#define SB_SCAT 625            // scatter: 625 blocks * 256 thr * 4 edges = 640000
#define SB_WPRE 512            // wprep:   512 blocks * 256 = 131072 elements
#define SB_XIN  2500           // xin:     2500 blocks * 16 nodes = 40000

typedef __bf16 bf16x8 __attribute__((ext_vector_type(8)));
typedef float  f32x4  __attribute__((ext_vector_type(4)));

__device__ inline unsigned short f2bf(float f) {
    __hip_bfloat16 b = __float2bfloat16(f);
    return *(unsigned short*)&b;
}
__device__ inline float bf2f(unsigned short u) {
    __hip_bfloat16 b = *(__hip_bfloat16*)&u;
    return __bfloat162float(b);
}

// ---- setup mega-kernel: [scatter | wprep(W-fold) | xin] by block range ----
// xin now writes ONLY x0bf (layer 0 reads x0bf directly as h_in; h is
// double-buffered across layers) -> saves 10 MB of setup writes.
__global__ __launch_bounds__(256) void k_setup(
        const int* __restrict__ row, const int* __restrict__ col,
        const float* __restrict__ w, int* __restrict__ cnt,
        unsigned int* __restrict__ bucket,
        const float* __restrict__ Wconv, unsigned short* __restrict__ Wtbf,
        const float* __restrict__ x, const float* __restrict__ Win,
        const float* __restrict__ bin,
        unsigned short* __restrict__ x0bf) {
    __shared__ float sW[H * FIN];      // used by xin branch only (16.9 KB)
    __shared__ float sx[16][FIN];
    int b = blockIdx.x, t = threadIdx.x;

    if (b < SB_SCAT) {
        // bucket scatter: 4 independent chains/thread; record = [bf16 w | col]
        int e0 = (b * 256 + t) * 4;
        int r[4], pos[4];
        unsigned int rec[4];
        #pragma unroll
        for (int i = 0; i < 4; i++) {
            int e = e0 + i;
            r[i] = row[e];
            unsigned int wb = f2bf((1.0f - ALPHA) * w[e]);
            rec[i] = (wb << 16) | (unsigned int)col[e];
        }
        #pragma unroll
        for (int i = 0; i < 4; i++) pos[i] = atomicAdd(&cnt[r[i]], 1);
        #pragma unroll
        for (int i = 0; i < 4; i++) bucket[(size_t)r[i] * CAP + pos[i]] = rec[i];
        return;
    }
    if (b < SB_SCAT + SB_WPRE) {
        // W' = (1-beta)*I + beta*W, transposed to [l][j][k], bf16.
        int idx = (b - SB_SCAT) * 256 + t;        // = l*16384 + k*128 + j
        int l = idx >> 14;
        int rem = idx & 16383;
        int k = rem >> 7, j = rem & 127;
        float beta = logf(THETA / (float)(l + 1) + 1.0f);
        float v = beta * Wconv[idx];
        if (j == k) v += 1.0f - beta;
        Wtbf[l * 16384 + j * 128 + k] = f2bf(v);
        return;
    }
    {
        // x0 = relu(x @ W_in^T + b_in) -> bf16
        int n0 = (b - SB_SCAT - SB_WPRE) * 16;
        for (int i = t; i < H * FIN; i += 256) sW[i] = Win[i];
        for (int i = t; i < 16 * FIN; i += 256)
            sx[i / FIN][i % FIN] = x[(size_t)(n0 + i / FIN) * FIN + (i % FIN)];
        __syncthreads();
        int f = t % H;
        int l0 = t / H;
        float bv = bin[f];
        for (int lo = l0; lo < 16; lo += 2) {
            float acc = bv;
            #pragma unroll
            for (int k = 0; k < FIN; k++) acc += sx[lo][k] * sW[f * FIN + k];
            acc = fmaxf(acc, 0.f);
            x0bf[(size_t)(n0 + lo) * H + f] = f2bf(acc);
        }
    }
}

// ---- fused layer: spmm -> LDS -> MFMA GEMM -> residual/store (coalesced) --
// block = 256 thr (4 waves), 32 rows. h double-buffered (hin read-only, hout
// write-only) so the fusion has no intra-dispatch read/write race.
// Phase 1: wave w computes xx rows w*8..w*8+7 (16-lane row slices, 4 edge
//          slots), writes bf16 xx tile to LDS (row stride 272 B -> 2-way max).
// Phase 2: 4 waves split 32x128 output: rows (wv>>1)*16, cols (wv&1)*64;
//          16 MFMAs/wave from LDS A-frags + global Wt B-frags.
// Phase 3: acc -> LDS fp32, then cooperative coalesced epilogue: uint4 loads
//          of hin, residual+relu, uint4 stores of hout (or out-projection).
__global__ __launch_bounds__(256) void k_layer(
        const int* __restrict__ cnt, const unsigned int* __restrict__ bucket,
        const unsigned short* __restrict__ hin,
        const unsigned short* __restrict__ x0bf,
        const unsigned short* __restrict__ Wt,
        unsigned short* __restrict__ hout,
        const float* __restrict__ Wout, const float* __restrict__ bout,
        float* __restrict__ out, int do_out) {
    __shared__ __align__(16) char smem[16896];   // union: bf16 xx[32][136] / f32 acc[32][132]

    int t = threadIdx.x;
    int wv = t >> 6, lane = t & 63;
    int rbase = blockIdx.x * 32;

    // ---------------- phase 1: spmm into LDS ----------------
    {
        int slot = lane >> 4;              // 0..3: edge within a group of 4
        int fid  = lane & 15;              // feature block: features fid*8..+7
        for (int i = 0; i < 8; i++) {
            int rloc = wv * 8 + i;
            int row  = rbase + rloc;
            int deg  = cnt[row];
            const unsigned int* ep = bucket + (size_t)row * CAP;
            float acc[8] = {0,0,0,0,0,0,0,0};

            for (int e = 0; e < deg; e += 16) {
                unsigned int u[4];
                uint4 q[4];
                #pragma unroll
                for (int k = 0; k < 4; k++) {
                    int ei = e + k * 4 + slot;           // < CAP always
                    unsigned int uu = ep[ei];
                    u[k] = (ei < deg) ? uu : 0u;
                }
                #pragma unroll
                for (int k = 0; k < 4; k++)
                    q[k] = *(const uint4*)(hin + (size_t)(u[k] & 0xffffu) * H + fid * 8);
                #pragma unroll
                for (int k = 0; k < 4; k++) {
                    float w = bf2f((unsigned short)(u[k] >> 16));
                    acc[0] += w * bf2f((unsigned short)(q[k].x & 0xffffu));
                    acc[1] += w * bf2f((unsigned short)(q[k].x >> 16));
                    acc[2] += w * bf2f((unsigned short)(q[k].y & 0xffffu));
                    acc[3] += w * bf2f((unsigned short)(q[k].y >> 16));
                    acc[4] += w * bf2f((unsigned short)(q[k].z & 0xffffu));
                    acc[5] += w * bf2f((unsigned short)(q[k].z >> 16));
                    acc[6] += w * bf2f((unsigned short)(q[k].w & 0xffffu));
                    acc[7] += w * bf2f((unsigned short)(q[k].w >> 16));
                }
            }
            #pragma unroll
            for (int j = 0; j < 8; j++) {
                acc[j] += __shfl_xor(acc[j], 16);
                acc[j] += __shfl_xor(acc[j], 32);
            }
            if (slot == 0) {               // lanes 0..15 hold the full row
                uint4 xq = *(const uint4*)(x0bf + (size_t)row * H + fid * 8);
                float o0 = acc[0] + ALPHA * bf2f((unsigned short)(xq.x & 0xffffu));
                float o1 = acc[1] + ALPHA * bf2f((unsigned short)(xq.x >> 16));
                float o2 = acc[2] + ALPHA * bf2f((unsigned short)(xq.y & 0xffffu));
                float o3 = acc[3] + ALPHA * bf2f((unsigned short)(xq.y >> 16));
                float o4 = acc[4] + ALPHA * bf2f((unsigned short)(xq.z & 0xffffu));
                float o5 = acc[5] + ALPHA * bf2f((unsigned short)(xq.z >> 16));
                float o6 = acc[6] + ALPHA * bf2f((unsigned short)(xq.w & 0xffffu));
                float o7 = acc[7] + ALPHA * bf2f((unsigned short)(xq.w >> 16));
                uint4 r;
                r.x = (unsigned int)f2bf(o0) | ((unsigned int)f2bf(o1) << 16);
                r.y = (unsigned int)f2bf(o2) | ((unsigned int)f2bf(o3) << 16);
                r.z = (unsigned int)f2bf(o4) | ((unsigned int)f2bf(o5) << 16);
                r.w = (unsigned int)f2bf(o6) | ((unsigned int)f2bf(o7) << 16);
                *(uint4*)(smem + (size_t)rloc * 272 + fid * 16) = r;
            }
        }
    }
    __syncthreads();

    // ---------------- phase 2: MFMA GEMM from LDS ----------------
    int quad = lane >> 4, l16 = lane & 15;
    int rh = (wv >> 1) * 16;               // row half of this wave
    int ch = (wv & 1) * 64;                // col half of this wave
    f32x4 acc2[4];
    #pragma unroll
    for (int j = 0; j < 4; j++) acc2[j] = (f32x4){0.f, 0.f, 0.f, 0.f};

    #pragma unroll
    for (int k0 = 0; k0 < 4; k0++) {
        bf16x8 av = *(const bf16x8*)(smem + (size_t)(rh + l16) * 272 + k0 * 64 + quad * 16);
        #pragma unroll
        for (int j = 0; j < 4; j++) {
            bf16x8 bv = *(const bf16x8*)(Wt + (size_t)(ch + j * 16 + l16) * H + k0 * 32 + quad * 8);
            acc2[j] = __builtin_amdgcn_mfma_f32_16x16x32_bf16(av, bv, acc2[j], 0, 0, 0);
        }
    }
    __syncthreads();                       // all A-frag reads done; smem reusable

    // ---------------- phase 3a: acc -> LDS fp32 ----------------
    float* facc = (float*)smem;
    #pragma unroll
    for (int j = 0; j < 4; j++) {
        #pragma unroll
        for (int r = 0; r < 4; r++)
            facc[(rh + quad * 4 + r) * 132 + ch + j * 16 + l16] = acc2[j][r];
    }
    __syncthreads();

    // ---------------- phase 3b: coalesced epilogue ----------------
    // thread t handles cols (t&15)*8..+7 of rows (t>>4) and (t>>4)+16
    int cb = (t & 15) * 8;
    #pragma unroll
    for (int p = 0; p < 2; p++) {
        int rloc = p * 16 + (t >> 4);
        int row  = rbase + rloc;
        const float* fr = facc + rloc * 132 + cb;
        f32x4 a0 = *(const f32x4*)fr;
        f32x4 a1 = *(const f32x4*)(fr + 4);
        uint4 hq = *(const uint4*)(hin + (size_t)row * H + cb);
        float hv[8];
        hv[0] = bf2f((unsigned short)(hq.x & 0xffffu)) + fmaxf(a0[0], 0.f);
        hv[1] = bf2f((unsigned short)(hq.x >> 16))     + fmaxf(a0[1], 0.f);
        hv[2] = bf2f((unsigned short)(hq.y & 0xffffu)) + fmaxf(a0[2], 0.f);
        hv[3] = bf2f((unsigned short)(hq.y >> 16))     + fmaxf(a0[3], 0.f);
        hv[4] = bf2f((unsigned short)(hq.z & 0xffffu)) + fmaxf(a1[0], 0.f);
        hv[5] = bf2f((unsigned short)(hq.z >> 16))     + fmaxf(a1[1], 0.f);
        hv[6] = bf2f((unsigned short)(hq.w & 0xffffu)) + fmaxf(a1[2], 0.f);
        hv[7] = bf2f((unsigned short)(hq.w >> 16))     + fmaxf(a1[3], 0.f);

        if (!do_out) {
            uint4 rr;
            rr.x = (unsigned int)f2bf(hv[0]) | ((unsigned int)f2bf(hv[1]) << 16);
            rr.y = (unsigned int)f2bf(hv[2]) | ((unsigned int)f2bf(hv[3]) << 16);
            rr.z = (unsigned int)f2bf(hv[4]) | ((unsigned int)f2bf(hv[5]) << 16);
            rr.w = (unsigned int)f2bf(hv[6]) | ((unsigned int)f2bf(hv[7]) << 16);
            *(uint4*)(hout + (size_t)row * H + cb) = rr;
        } else {
            // last layer: out = h @ Wout^T + bout, reduced over 16 lanes/row
            float p0 = 0.f, p1 = 0.f, p2 = 0.f;
            #pragma unroll
            for (int i2 = 0; i2 < 8; i2++) {
                float h = hv[i2];
                p0 += h * Wout[cb + i2];
                p1 += h * Wout[H + cb + i2];
                p2 += h * Wout[2 * H + cb + i2];
            }
            #pragma unroll
            for (int off = 1; off < 16; off <<= 1) {
                p0 += __shfl_xor(p0, off);
                p1 += __shfl_xor(p1, off);
                p2 += __shfl_xor(p2, off);
            }
            if ((t & 15) == 0) {
                out[(size_t)row * 3 + 0] = p0 + bout[0];
                out[(size_t)row * 3 + 1] = p1 + bout[1];
                out[(size_t)row * 3 + 2] = p2 + bout[2];
            }
        }
    }
}

extern "C" void kernel_launch(void* const* d_in, const int* in_sizes, int n_in,
                              void* d_out, int out_size, void* d_ws, size_t ws_size,
                              hipStream_t stream) {
    const float* x     = (const float*)d_in[0];
    const int*   erow  = (const int*)  d_in[1];
    const int*   ecol  = (const int*)  d_in[2];
    const float* ew    = (const float*)d_in[3];
    const float* Win   = (const float*)d_in[4];
    const float* bin   = (const float*)d_in[5];
    const float* Wout  = (const float*)d_in[6];
    const float* bout  = (const float*)d_in[7];
    const float* Wconv = (const float*)d_in[8];
    float* out = (float*)d_out;

    char* ws = (char*)d_ws;
    const size_t NHb = (size_t)N_NODES * H * sizeof(unsigned short);  // 10,240,000
    unsigned short* x0bf  = (unsigned short*)(ws);
    unsigned short* bufA  = (unsigned short*)(ws + NHb);
    unsigned short* bufB  = (unsigned short*)(ws + 2 * NHb);
    char* p = ws + 3 * NHb;
    unsigned short* Wtbf  = (unsigned short*)p;  p += 8 * H * H * 2;  // 262,144
    int*  cnt     = (int*) p;  p += 160256;                           // N ints, padded
    unsigned int* bucket = (unsigned int*)p;     // N * CAP * 4 = 15,360,000 B

    // zero bucket counters, then one mega-dispatch: scatter + W-fold + xin
    hipMemsetAsync(cnt, 0, (size_t)N_NODES * 4, stream);
    k_setup<<<SB_SCAT + SB_WPRE + SB_XIN, 256, 0, stream>>>(
        erow, ecol, ew, cnt, bucket, Wconv, Wtbf, x, Win, bin, x0bf);

    // fused layers; h ping-pongs: x0 -> A -> B -> A -> ... (read/write
    // buffers disjoint each layer, so spmm gathers never race with stores)
    for (int l = 0; l < NLAYERS; l++) {
        const unsigned short* hin = (l == 0) ? x0bf : ((l & 1) ? bufA : bufB);
        unsigned short* hout = (l & 1) ? bufB : bufA;
        k_layer<<<N_NODES / 32, 256, 0, stream>>>(
            cnt, bucket, hin, x0bf, Wtbf + (size_t)l * H * H,
            hout, Wout, bout, out, (l == NLAYERS - 1) ? 1 : 0);
    }
}